// Round 4
// baseline (28833.240 us; speedup 1.0000x reference)
//
#include <hip/hip_runtime.h>

#define HIDDEN   2048
#define T_STEPS  8192
#define WASHOUT  200
#define NWG      128
#define NTHR     512
#define NWAVE    (NTHR / 64)                 // 8 waves
#define ROWS_PER_WG   (HIDDEN / NWG)         // 16
#define ROWS_PER_WAVE (ROWS_PER_WG / NWAVE)  // 2
#define MB       8                           // float4 col-blocks per lane

// ws layout: unsigned long long pairs[2][HIDDEN] -- {value:hi32, step:lo32}.
// Single 8B atomic carries payload+tag: no fences, no flags, one round trip.
// 0xAA poison -> tag 0xAAAAAAAA never matches a real step: self-initializing.

__global__ __launch_bounds__(NTHR, 1) void esn_main(
    const float* __restrict__ u,
    const float* __restrict__ w_in,
    const float* __restrict__ w_res,
    const float* __restrict__ w_out,
    float* __restrict__ out,
    unsigned long long* __restrict__ pairs)
{
  const int g  = blockIdx.x;    // 0..127, one WG per CU
  const int j  = threadIdx.x;   // 0..511
  const int wv = j >> 6;        // 0..7
  const int l  = j & 63;

  __shared__ float x_s[2][HIDDEN];   // double-buffered staged state (16 KB)
  __shared__ float u_s[T_STEPS];     // 32 KB
  __shared__ float red[NWAVE];

#pragma unroll
  for (int k = 0; k < T_STEPS / NTHR; ++k) u_s[j + NTHR * k] = u[j + NTHR * k];

  // wave wv owns rows r0, r0+1; lane l owns cols {mb*256 + 4l .. +3}
  const int r0 = g * ROWS_PER_WG + wv * ROWS_PER_WAVE;

  float4 wr0[MB], wr1[MB];   // 64 floats/thread -- must stay VGPR-resident
#pragma unroll
  for (int mb = 0; mb < MB; ++mb) {
    wr0[mb] = *(const float4*)&w_res[(r0 + 0) * HIDDEN + mb * 256 + 4 * l];
    wr1[mb] = *(const float4*)&w_res[(r0 + 1) * HIDDEN + mb * 256 + 4 * l];
  }
#pragma unroll
  for (int mb = 0; mb < MB; ++mb) {
    asm volatile("" : "+v"(wr0[mb].x), "+v"(wr0[mb].y),
                      "+v"(wr0[mb].z), "+v"(wr0[mb].w));
    asm volatile("" : "+v"(wr1[mb].x), "+v"(wr1[mb].y),
                      "+v"(wr1[mb].z), "+v"(wr1[mb].w));
  }

  const float win0 = w_in[r0];
  const float win1 = w_in[r0 + 1];
  const float4 wo  = *(const float4*)&w_out[4 * j];

  __syncthreads();  // u_s ready

  for (int t = 0; t < T_STEPS; ++t) {
    float d0 = 0.f, d1 = 0.f;
    if (t > 0) {
      const unsigned sp   = (unsigned)((t - 1) & 1);
      const unsigned want = (unsigned)(t - 1);
      const unsigned long long* bp = pairs + sp * HIDDEN;
      float4 xv;
      float* xvp = &xv.x;
      // thread j owns rows [4j, 4j+4) -- all from one producer WG (j/4)
#pragma unroll
      for (int k = 0; k < 4; ++k) {
        unsigned long long p = __hip_atomic_load(bp + 4 * j + k, __ATOMIC_RELAXED,
                                                 __HIP_MEMORY_SCOPE_AGENT);
        while ((unsigned)p != want)
          p = __hip_atomic_load(bp + 4 * j + k, __ATOMIC_RELAXED,
                                __HIP_MEMORY_SCOPE_AGENT);
        xvp[k] = __uint_as_float((unsigned)(p >> 32));
      }
      ((float4*)x_s[sp])[j] = xv;
      __syncthreads();  // staging complete (single barrier per step)

      const float4* xs4 = (const float4*)x_s[sp];
#pragma unroll
      for (int mb = 0; mb < MB; ++mb) {
        const float4 x4 = xs4[mb * 64 + l];   // ds_read_b128
        d0 = fmaf(wr0[mb].x, x4.x, d0); d0 = fmaf(wr0[mb].y, x4.y, d0);
        d0 = fmaf(wr0[mb].z, x4.z, d0); d0 = fmaf(wr0[mb].w, x4.w, d0);
        d1 = fmaf(wr1[mb].x, x4.x, d1); d1 = fmaf(wr1[mb].y, x4.y, d1);
        d1 = fmaf(wr1[mb].z, x4.z, d1); d1 = fmaf(wr1[mb].w, x4.w, d1);
      }
    }
#pragma unroll
    for (int off = 32; off >= 1; off >>= 1) {
      d0 += __shfl_xor(d0, off, 64);
      d1 += __shfl_xor(d1, off, 64);
    }
    const float ut = u_s[t];
    if (l < ROWS_PER_WAVE) {
      const float dsel = (l == 0) ? d0 : d1;
      const float wsel = (l == 0) ? win0 : win1;
      const float xn = tanhf(fmaf(wsel, ut, dsel));
      const unsigned long long pk =
          ((unsigned long long)__float_as_uint(xn) << 32) | (unsigned)t;
      // publish immediately: payload+tag in one atomic, no drain, no flag
      __hip_atomic_store(pairs + (t & 1) * HIDDEN + r0 + l, pk,
                         __ATOMIC_RELAXED, __HIP_MEMORY_SCOPE_AGENT);
    }

    // readout of x[t-1] (staged in x_s[(t-1)&1]), rotating WG, off critical path
    if (t >= WASHOUT + 1 && g == (t & (NWG - 1))) {
      const float4 xv = ((const float4*)x_s[(t - 1) & 1])[j];
      float p = fmaf(xv.x, wo.x, fmaf(xv.y, wo.y, fmaf(xv.z, wo.z, xv.w * wo.w)));
#pragma unroll
      for (int off = 32; off >= 1; off >>= 1) p += __shfl_xor(p, off, 64);
      if (l == 0) red[wv] = p;
      __syncthreads();
      if (j == 0) {
        float s = 0.f;
#pragma unroll
        for (int i = 0; i < NWAVE; ++i) s += red[i];
        out[t - 1 - WASHOUT] = s;
      }
    }
  }

  // epilogue: out[T-1-WASHOUT] = x[T-1] . w_out  (WG 0)
  if (g == 0) {
    const unsigned sp   = (unsigned)((T_STEPS - 1) & 1);
    const unsigned want = (unsigned)(T_STEPS - 1);
    const unsigned long long* bp = pairs + sp * HIDDEN;
    float4 xv;
    float* xvp = &xv.x;
#pragma unroll
    for (int k = 0; k < 4; ++k) {
      unsigned long long p = __hip_atomic_load(bp + 4 * j + k, __ATOMIC_RELAXED,
                                               __HIP_MEMORY_SCOPE_AGENT);
      while ((unsigned)p != want)
        p = __hip_atomic_load(bp + 4 * j + k, __ATOMIC_RELAXED,
                              __HIP_MEMORY_SCOPE_AGENT);
      xvp[k] = __uint_as_float((unsigned)(p >> 32));
    }
    ((float4*)x_s[sp])[j] = xv;
    __syncthreads();
    const float4 x4 = ((const float4*)x_s[sp])[j];
    float p = fmaf(x4.x, wo.x, fmaf(x4.y, wo.y, fmaf(x4.z, wo.z, x4.w * wo.w)));
#pragma unroll
    for (int off = 32; off >= 1; off >>= 1) p += __shfl_xor(p, off, 64);
    if (l == 0) red[wv] = p;
    __syncthreads();
    if (j == 0) {
      float s = 0.f;
#pragma unroll
      for (int i = 0; i < NWAVE; ++i) s += red[i];
      out[T_STEPS - 1 - WASHOUT] = s;
    }
  }
}

extern "C" void kernel_launch(void* const* d_in, const int* in_sizes, int n_in,
                              void* d_out, int out_size, void* d_ws, size_t ws_size,
                              hipStream_t stream) {
  const float* u     = (const float*)d_in[0];
  const float* w_in  = (const float*)d_in[1];
  const float* w_res = (const float*)d_in[2];
  const float* w_out = (const float*)d_in[3];
  float* out = (float*)d_out;
  unsigned long long* pairs = (unsigned long long*)d_ws;

  esn_main<<<NWG, NTHR, 0, stream>>>(u, w_in, w_res, w_out, out, pairs);
}